// Round 20
// baseline (84.377 us; speedup 1.0000x reference)
//
#include <hip/hip_runtime.h>
#include <hip/hip_bf16.h>
#include <math.h>

// Problem constants
#define NB 4
#define NSQ 2048
#define NSKV 2048
#define ND 768
#define NH 12
#define NHD 16
#define NDR 192            // NH*NHD
#define M_TOT (NB * NSQ)   // 8192

typedef __attribute__((ext_vector_type(8)))  short          bf16x8;
typedef __attribute__((ext_vector_type(16))) float          f32x16;
typedef __attribute__((ext_vector_type(8)))  unsigned short u16x8;

__device__ __forceinline__ unsigned short bfbits(float x) {
  __hip_bfloat16 h = __float2bfloat16(x);           // hardware RNE cvt
  unsigned short u; __builtin_memcpy(&u, &h, 2); return u;
}
__device__ __forceinline__ float bf2f(unsigned short u) {
  unsigned int v = ((unsigned int)u) << 16; float f; __builtin_memcpy(&f, &v, 4); return f;
}
// P-pack: truncating bf16 pack of two NEVER-NaN positives in ONE v_perm_b32.
__device__ __forceinline__ unsigned int pk2t(float a, float b) {
  unsigned int ua, ub;
  __builtin_memcpy(&ua, &a, 4); __builtin_memcpy(&ub, &b, 4);
#if __has_builtin(__builtin_amdgcn_perm)
  return __builtin_amdgcn_perm(ub, ua, 0x07060302);  // {b.hi16, a.hi16}
#else
  return (ua >> 16) | (ub & 0xffff0000u);
#endif
}
__device__ __forceinline__ float exp2_raw(float x) {
#if __has_builtin(__builtin_amdgcn_exp2f)
  return __builtin_amdgcn_exp2f(x);                 // single v_exp_f32
#else
  float r; asm("v_exp_f32 %0, %1" : "=v"(r) : "v"(x)); return r;
#endif
}
__device__ __forceinline__ void g2l16(const void* g, void* l) {
  __builtin_amdgcn_global_load_lds(
      (const __attribute__((address_space(1))) void*)g,
      (__attribute__((address_space(3))) void*)l, 16, 0, 0);
}

// 0.25 (1/sqrt(HD)) * log2(e): attention runs in exp2 domain
#define QSCALE 0.36067376022224085f
#define LDSBUF 16384   // shorts per dbuf half for gemm_out: (64+192)*64

// ---------------------------------------------------------------------------
// prep: the three weight splits
// (fp32 W [K][N] -> swizzled split-bf16 W^T image [N][KBLK][8][8]).
// ---------------------------------------------------------------------------
__global__ __launch_bounds__(256) void prep(
    const float* __restrict__ Wq, const float* __restrict__ Wkv,
    const float* __restrict__ Wp,
    unsigned short* __restrict__ WSq, unsigned short* __restrict__ WSkv,
    unsigned short* __restrict__ WSp) {
  int bid = blockIdx.x;
  const float* W; unsigned short* out; int Nn, KBLK, bx, by;
  if (bid < 72)        { W = Wq;  out = WSq;  Nn = 192; KBLK = 24; bx = bid % 24;        by = bid / 24; }
  else if (bid < 216)  { int b = bid - 72;  W = Wkv; out = WSkv; Nn = 384; KBLK = 24; bx = b % 24; by = b / 24; }
  else                 { int b = bid - 216; W = Wp;  out = WSp;  Nn = 768; KBLK = 6;  bx = b % 6;  by = b / 6;  }

  __shared__ float tile[32][65];
  int k0 = bx * 32, n0 = by * 64;
  int t = threadIdx.x;
  int kr = t >> 3, c0 = (t & 7) * 8;
  const float* src = W + (size_t)(k0 + kr) * Nn + n0 + c0;
  float4 f0 = *reinterpret_cast<const float4*>(src);
  float4 f1 = *reinterpret_cast<const float4*>(src + 4);
  tile[kr][c0+0] = f0.x; tile[kr][c0+1] = f0.y; tile[kr][c0+2] = f0.z; tile[kr][c0+3] = f0.w;
  tile[kr][c0+4] = f1.x; tile[kr][c0+5] = f1.y; tile[kr][c0+6] = f1.z; tile[kr][c0+7] = f1.w;
  __syncthreads();
  int n = t >> 2, cq0 = (t & 3) * 2;
  int ng = n0 + n, sw = ng & 7;
  unsigned short* dst = out + ((size_t)ng * KBLK + bx) * 64;
  #pragma unroll
  for (int q = 0; q < 2; ++q) {
    int cc = cq0 + q;                // logical chunk 0..7
    u16x8 v;
    #pragma unroll
    for (int i = 0; i < 8; ++i) {
      float x = tile[(cc & 3) * 8 + i][n];
      unsigned short h = bfbits(x);
      v[i] = (cc < 4) ? h : bfbits(x - bf2f(h));
    }
    *reinterpret_cast<u16x8*>(dst + (cc ^ sw) * 8) = v;
  }
}

// ---------------------------------------------------------------------------
// gemm_out core (image-A, double-buffered, 64x192, 4 waves) — unchanged.
// ---------------------------------------------------------------------------
__device__ __forceinline__ void core_compute(
    const unsigned short* const (&ard)[4], const unsigned short* const (&wrd)[12],
    int off, f32x16 (&acc)[3]) {
  #pragma unroll
  for (int kk = 0; kk < 2; ++kk) {
    bf16x8 ah = *reinterpret_cast<const bf16x8*>(ard[kk*2+0] + off);
    bf16x8 al = *reinterpret_cast<const bf16x8*>(ard[kk*2+1] + off);
    #pragma unroll
    for (int nr = 0; nr < 3; ++nr) {
      bf16x8 wh = *reinterpret_cast<const bf16x8*>(wrd[(nr*2+kk)*2+0] + off);
      bf16x8 wl = *reinterpret_cast<const bf16x8*>(wrd[(nr*2+kk)*2+1] + off);
      acc[nr] = __builtin_amdgcn_mfma_f32_32x32x16_bf16(ah, wh, acc[nr], 0, 0, 0);
      acc[nr] = __builtin_amdgcn_mfma_f32_32x32x16_bf16(ah, wl, acc[nr], 0, 0, 0);
      acc[nr] = __builtin_amdgcn_mfma_f32_32x32x16_bf16(al, wh, acc[nr], 0, 0, 0);
    }
  }
}

__device__ __forceinline__ void gemm_core(
    const unsigned short* __restrict__ As,   // pre-offset to m0
    const unsigned short* __restrict__ Ws,   // pre-offset to n0
    const float* __restrict__ bias,          // pre-offset to n0
    int KBLK, unsigned short* lds, f32x16 (&acc)[3]) {
  const int tid = threadIdx.x;
  const int wv = tid >> 6, lane = tid & 63;
  const int l31 = lane & 31, hi8 = lane >> 5;
  const int wm = wv >> 1, wn = wv & 1;

  unsigned short* Ab = lds;
  unsigned short* Wb = lds + 64 * 64;

  const int r8 = lane >> 3, c8 = lane & 7;
  const size_t rowu = (size_t)KBLK * 64;

  const unsigned short* srcA0 = As + (size_t)((0*4 + wv)*8 + r8) * rowu + c8*8;
  const unsigned short* srcA1 = As + (size_t)((1*4 + wv)*8 + r8) * rowu + c8*8;
  const unsigned short* srcW[6];
  #pragma unroll
  for (int j = 0; j < 6; ++j)
    srcW[j] = Ws + (size_t)((j*4 + wv)*8 + r8) * rowu + c8*8;

  unsigned short* dA0 = Ab + ((0*4 + wv)*64 + lane) * 8;
  unsigned short* dA1 = Ab + ((1*4 + wv)*64 + lane) * 8;
  unsigned short* dW[6];
  #pragma unroll
  for (int j = 0; j < 6; ++j)
    dW[j] = Wb + ((j*4 + wv)*64 + lane) * 8;

  const int ra = wm*32 + l31;
  const unsigned short* ard[4];
  #pragma unroll
  for (int kk = 0; kk < 2; ++kk) {
    ard[kk*2+0] = Ab + ra*64 + (((kk*2 + hi8)     ^ (ra & 7)) * 8);
    ard[kk*2+1] = Ab + ra*64 + (((4 + kk*2 + hi8) ^ (ra & 7)) * 8);
  }
  const unsigned short* wrd[12];
  #pragma unroll
  for (int nr = 0; nr < 3; ++nr) {
    int rw = wn*96 + nr*32 + l31;
    #pragma unroll
    for (int kk = 0; kk < 2; ++kk) {
      wrd[(nr*2+kk)*2+0] = Wb + rw*64 + (((kk*2 + hi8)     ^ (rw & 7)) * 8);
      wrd[(nr*2+kk)*2+1] = Wb + rw*64 + (((4 + kk*2 + hi8) ^ (rw & 7)) * 8);
    }
  }

  #pragma unroll
  for (int nr = 0; nr < 3; ++nr) {
    float bv = bias[wn*96 + nr*32 + l31];
    #pragma unroll
    for (int r = 0; r < 16; ++r) acc[nr][r] = bv;
  }

  g2l16(srcA0, dA0); srcA0 += 64;
  g2l16(srcA1, dA1); srcA1 += 64;
  #pragma unroll
  for (int j = 0; j < 6; ++j) { g2l16(srcW[j], dW[j]); srcW[j] += 64; }
  __syncthreads();

  for (int kb = 0; kb < KBLK; kb += 2) {
    if (kb + 1 < KBLK) {
      g2l16(srcA0, dA0 + LDSBUF); srcA0 += 64;
      g2l16(srcA1, dA1 + LDSBUF); srcA1 += 64;
      #pragma unroll
      for (int j = 0; j < 6; ++j) { g2l16(srcW[j], dW[j] + LDSBUF); srcW[j] += 64; }
    }
    core_compute(ard, wrd, 0, acc);
    __syncthreads();
    if (kb + 2 < KBLK) {
      g2l16(srcA0, dA0); srcA0 += 64;
      g2l16(srcA1, dA1); srcA1 += 64;
      #pragma unroll
      for (int j = 0; j < 6; ++j) { g2l16(srcW[j], dW[j]); srcW[j] += 64; }
    }
    core_compute(ard, wrd, LDSBUF, acc);
    __syncthreads();
  }
}

// ---------------------------------------------------------------------------
// Fused Q/KV projection (R16 verified, 64x96 tiles, 6 waves, 40 KiB dbuf)
// + XCD-locality remap: blocks sharing an A-tile land on one XCD.
// ---------------------------------------------------------------------------
#define QHALF 10240   // shorts per buffer: A 64x64 + W 96x64
__global__ __launch_bounds__(384) void gemm_qkv(
    const float* __restrict__ A1, const float* __restrict__ A2,
    const unsigned short* __restrict__ WSq, const unsigned short* __restrict__ WSkv,
    const float* __restrict__ bq, const float* __restrict__ bkv,
    unsigned short* __restrict__ Qbf, unsigned short* __restrict__ Kbf,
    unsigned short* __restrict__ VTbf) {
  __shared__ unsigned short lds[2 * QHALF];   // 40 KiB
  const int bid = blockIdx.x;
  const float* Afp; const unsigned short* Ws; const float* bias;
  int m0, mode, ntile;
  if (bid < 256) {
    mode = 0; ntile = (bid >> 7) * 96;        // XCD remap: mt-major
    Afp = A1; Ws = WSq + (size_t)ntile * (24*64); bias = bq + ntile;
    m0 = (bid & 127) * 64;
  } else {
    int b2 = bid - 256;
    int sub = b2 >> 7;                        // XCD remap: mt-major
    m0 = (b2 & 127) * 64;
    Afp = A2;
    if (sub < 2) { mode = 1; ntile = sub * 96;
                   Ws = WSkv + (size_t)ntile * (24*64); bias = bkv + ntile; }
    else         { mode = 2; ntile = (sub - 2) * 96;
                   Ws = WSkv + (size_t)(192 + ntile) * (24*64); bias = bkv + 192 + ntile; }
  }
  Afp += (size_t)m0 * ND;

  const int tid = threadIdx.x;
  const int wv = tid >> 6, lane = tid & 63;
  const int l31 = lane & 31, hi8 = lane >> 5;
  const int wm = wv & 1, wn = wv >> 1;    // wm 0..1 (rows), wn 0..2 (cols)

  unsigned short* Ab = lds;               // [64][64]
  unsigned short* Wb = lds + 64*64;       // [96][64]

  // A staging (threads 0..255): row ar, fp32 quad cq
  const int ar = tid >> 2, cq = tid & 3;
  const bool doA = (tid < 256);
  const float* srcA = Afp + (size_t)(doA ? ar : 0) * ND + cq*8;
  unsigned short* dAh = Ab + (doA ? ar : 0)*64 + ((cq       ^ (ar & 7)) * 8);
  unsigned short* dAl = Ab + (doA ? ar : 0)*64 + (((cq + 4) ^ (ar & 7)) * 8);

  // W staging: 2 physical chunks per thread (768 = 96 rows x 8)
  const int wch0 = tid, wch1 = tid + 384;
  const unsigned short* srcW0 = Ws + (size_t)(wch0 >> 3) * (24*64) + (wch0 & 7) * 8;
  const unsigned short* srcW1 = Ws + (size_t)(wch1 >> 3) * (24*64) + (wch1 & 7) * 8;
  unsigned short* dW0 = Wb + wch0 * 8;
  unsigned short* dW1 = Wb + wch1 * 8;

  // read-side fragment pointers (verified XOR-swizzle algebra)
  const int ra = wm*32 + l31;
  const int rw = wn*32 + l31;
  const unsigned short* ard[4];
  const unsigned short* wrd[4];
  #pragma unroll
  for (int kk = 0; kk < 2; ++kk) {
    ard[kk*2+0] = Ab + ra*64 + (((kk*2 + hi8)     ^ (ra & 7)) * 8);
    ard[kk*2+1] = Ab + ra*64 + (((4 + kk*2 + hi8) ^ (ra & 7)) * 8);
    wrd[kk*2+0] = Wb + rw*64 + (((kk*2 + hi8)     ^ (rw & 7)) * 8);
    wrd[kk*2+1] = Wb + rw*64 + (((4 + kk*2 + hi8) ^ (rw & 7)) * 8);
  }

  f32x16 acc;
  {
    float bv = bias[wn*32 + l31];
    #pragma unroll
    for (int r = 0; r < 16; ++r) acc[r] = bv;
  }

  // ---- prologue: stage k-step 0 -> buf0
  {
    g2l16(srcW0, dW0); srcW0 += 64;
    g2l16(srcW1, dW1); srcW1 += 64;
    if (doA) {
      float4 f0 = *reinterpret_cast<const float4*>(srcA);
      float4 f1 = *reinterpret_cast<const float4*>(srcA + 4);
      float x[8] = {f0.x, f0.y, f0.z, f0.w, f1.x, f1.y, f1.z, f1.w};
      u16x8 hv, lv;
      #pragma unroll
      for (int i = 0; i < 8; ++i) {
        unsigned short h = bfbits(x[i]);
        hv[i] = h; lv[i] = bfbits(x[i] - bf2f(h));
      }
      *reinterpret_cast<u16x8*>(dAh) = hv;
      *reinterpret_cast<u16x8*>(dAl) = lv;
    }
    srcA += 32;
  }
  __syncthreads();

  #define QKV_COMPUTE(off)                                                     \
    {                                                                          \
      _Pragma("unroll")                                                        \
      for (int kk = 0; kk < 2; ++kk) {                                         \
        bf16x8 ah = *reinterpret_cast<const bf16x8*>(ard[kk*2+0] + (off));     \
        bf16x8 al = *reinterpret_cast<const bf16x8*>(ard[kk*2+1] + (off));     \
        bf16x8 wh = *reinterpret_cast<const bf16x8*>(wrd[kk*2+0] + (off));     \
        bf16x8 wl = *reinterpret_cast<const bf16x8*>(wrd[kk*2+1] + (off));     \
        acc = __builtin_amdgcn_mfma_f32_32x32x16_bf16(ah, wh, acc, 0, 0, 0);   \
        acc = __builtin_amdgcn_mfma_f32_32x32x16_bf16(ah, wl, acc, 0, 0, 0);   \
        acc = __builtin_amdgcn_mfma_f32_32x32x16_bf16(al, wh, acc, 0, 0, 0);   \
      }                                                                        \
    }

  for (int kb = 0; kb < 24; kb += 2) {
    // phase A: stage kb+1 -> buf1, compute buf0
    float4 f0, f1;
    g2l16(srcW0, dW0 + QHALF); srcW0 += 64;
    g2l16(srcW1, dW1 + QHALF); srcW1 += 64;
    if (doA) {
      f0 = *reinterpret_cast<const float4*>(srcA);
      f1 = *reinterpret_cast<const float4*>(srcA + 4);
    }
    srcA += 32;
    QKV_COMPUTE(0)
    if (doA) {
      float x[8] = {f0.x, f0.y, f0.z, f0.w, f1.x, f1.y, f1.z, f1.w};
      u16x8 hv, lv;
      #pragma unroll
      for (int i = 0; i < 8; ++i) {
        unsigned short h = bfbits(x[i]);
        hv[i] = h; lv[i] = bfbits(x[i] - bf2f(h));
      }
      *reinterpret_cast<u16x8*>(dAh + QHALF) = hv;
      *reinterpret_cast<u16x8*>(dAl + QHALF) = lv;
    }
    __syncthreads();
    // phase B: stage kb+2 -> buf0, compute buf1
    bool has2 = (kb + 2 < 24);
    if (has2) {
      g2l16(srcW0, dW0); srcW0 += 64;
      g2l16(srcW1, dW1); srcW1 += 64;
      if (doA) {
        f0 = *reinterpret_cast<const float4*>(srcA);
        f1 = *reinterpret_cast<const float4*>(srcA + 4);
      }
      srcA += 32;
    }
    QKV_COMPUTE(QHALF)
    if (has2 && doA) {
      float x[8] = {f0.x, f0.y, f0.z, f0.w, f1.x, f1.y, f1.z, f1.w};
      u16x8 hv, lv;
      #pragma unroll
      for (int i = 0; i < 8; ++i) {
        unsigned short h = bfbits(x[i]);
        hv[i] = h; lv[i] = bfbits(x[i] - bf2f(h));
      }
      *reinterpret_cast<u16x8*>(dAh) = hv;
      *reinterpret_cast<u16x8*>(dAl) = lv;
    }
    __syncthreads();
  }
  #undef QKV_COMPUTE

  // ---- epilogues
  if (mode == 2) {
    // V: transpose via LDS -> VT2 [bh][key/8][16d][8key]
    unsigned short (*tile)[65] = reinterpret_cast<unsigned short(*)[65]>(lds);
    #pragma unroll
    for (int r = 0; r < 16; ++r) {
      int key_l = wm*32 + (r & 3) + 8*(r >> 2) + 4*hi8;   // 0..63
      tile[wn*32 + l31][key_l] = bfbits(acc[r]);
    }
    __syncthreads();
    int b = m0 >> 11, key0 = m0 & 2047;
    #pragma unroll
    for (int j = 0; j < 2; ++j) {
      int flat = j * 384 + tid;        // 0..767
      int row = flat >> 3;             // 0..95 local V-col
      int ck = flat & 7;               // 8-key chunk within the 64 keys
      int vcol = ntile + row;
      int h = vcol >> 4, d = vcol & 15;
      u16x8 v;
      #pragma unroll
      for (int jj = 0; jj < 8; ++jj) v[jj] = tile[row][ck*8 + jj];
      *reinterpret_cast<u16x8*>(
          &VTbf[(((size_t)(b*NH + h)*256 + (key0 >> 3) + ck)*16 + d)*8]) = v;
    }
    return;
  }

  unsigned short* outp = (mode == 0) ? Qbf : Kbf;
  const float scale = (mode == 0) ? QSCALE : 1.0f;
  {
    int col = ntile + wn*32 + l31;      // 0..191
    int h = col >> 4, d = col & 15;
    #pragma unroll
    for (int r = 0; r < 16; ++r) {
      int mg = m0 + wm*32 + (r & 3) + 8*(r >> 2) + 4*hi8;
      int b = mg >> 11, q = mg & 2047;
      outp[(((size_t)b*NH + h)*NSQ + q)*16 + d] = bfbits(acc[r] * scale);
    }
  }
}

// ---------------------------------------------------------------------------
// attn 32-key tile compute (verified R8/R10 algebra, pk2t pack,
// pre-selected 4-shfl exchange)
// ---------------------------------------------------------------------------
__device__ __forceinline__ void attn_tile32(
    bf16x8 qf, bf16x8 kf, bf16x8 vf0, bf16x8 vf1,
    int hi8, const f32x16& zeroc, f32x16& acc) {
  f32x16 s = __builtin_amdgcn_mfma_f32_32x32x16_bf16(kf, qf, zeroc, 0, 0, 0);

  float p[16];
  #pragma unroll
  for (int r = 0; r < 16; ++r) p[r] = exp2_raw(s[r]);

  unsigned int w[8];
  #pragma unroll
  for (int t8 = 0; t8 < 8; ++t8) w[t8] = pk2t(p[2*t8], p[2*t8+1]);

  unsigned int t0 = hi8 ? w[0] : w[2], t1 = hi8 ? w[1] : w[3];
  unsigned int t2 = hi8 ? w[4] : w[6], t3 = hi8 ? w[5] : w[7];
  unsigned int r0 = (unsigned int)__shfl_xor((int)t0, 32);
  unsigned int r1 = (unsigned int)__shfl_xor((int)t1, 32);
  unsigned int r2 = (unsigned int)__shfl_xor((int)t2, 32);
  unsigned int r3 = (unsigned int)__shfl_xor((int)t3, 32);

  union { bf16x8 v; unsigned int u[4]; } pa0, pa1;
  pa0.u[0] = hi8 ? r0 : w[0];  pa0.u[1] = hi8 ? r1 : w[1];
  pa0.u[2] = hi8 ? w[2] : r0;  pa0.u[3] = hi8 ? w[3] : r1;
  pa1.u[0] = hi8 ? r2 : w[4];  pa1.u[1] = hi8 ? r3 : w[5];
  pa1.u[2] = hi8 ? w[6] : r2;  pa1.u[3] = hi8 ? w[7] : r3;

  __builtin_amdgcn_s_setprio(1);
  acc = __builtin_amdgcn_mfma_f32_32x32x16_bf16(vf0, pa0.v, acc, 0, 0, 0);
  acc = __builtin_amdgcn_mfma_f32_32x32x16_bf16(vf1, pa1.v, acc, 0, 0, 0);
  __builtin_amdgcn_s_setprio(0);
}

// ---------------------------------------------------------------------------
// MFMA attention (R14/R16/R19 verified) + FULL UNROLL of the kt loop:
// compile-time trip count (8) lets the scheduler pipeline loads as deep as
// the launch_bounds VGPR cap allows (vs hand-written depth-2 dbuf).
// ---------------------------------------------------------------------------
__global__ __launch_bounds__(256, 4) void attn_bf16(
    const unsigned short* __restrict__ Qbf, const unsigned short* __restrict__ Kbf,
    const unsigned short* __restrict__ VT, unsigned short* __restrict__ AOS) {
  __shared__ float comb[4][64][9];
  const int tid = threadIdx.x;
  const int wave = tid >> 6, lane = tid & 63;
  const int l31 = lane & 31, hi8 = lane >> 5;
  const int bid = blockIdx.x;
  const int bh = bid % 48;           // XCD-locality remap (48 % 8 == 0)
  const int qt = bid / 48;           // 64 q-tiles of 32 rows
  const int q = qt * 32 + l31;

  bf16x8 qf = *reinterpret_cast<const bf16x8*>(&Qbf[((size_t)bh*NSQ + q)*16 + hi8*8]);
  const unsigned short* kbase = Kbf + (size_t)bh * NSKV * 16;

  const short fillv = (l31 == 16) ? (short)0x3F80 : (short)0;
  bf16x8 vfill;
  #pragma unroll
  for (int j = 0; j < 8; ++j) vfill[j] = fillv;

  f32x16 acc;
  #pragma unroll
  for (int r = 0; r < 16; ++r) acc[r] = 0.f;
  const f32x16 zeroc = acc;

  const int kstart = wave * (NSKV / 4);   // 512 keys per wave
  const unsigned short* kp = &kbase[(size_t)(kstart + l31)*16 + hi8*8];
  const unsigned short* vwave = VT + ((((size_t)bh*256 + (kstart >> 3) + hi8)*16 + l31) * 8);

  bf16x8 k0, v00, v10;
  bf16x8 k1, v01, v11;

  k0  = *reinterpret_cast<const bf16x8*>(kp);
  v00 = vfill; v10 = vfill;
  if (l31 < 16) {
    v00 = *reinterpret_cast<const bf16x8*>(vwave);
    v10 = *reinterpret_cast<const bf16x8*>(vwave + 256);
  }

  #pragma unroll
  for (int kt = 0; kt < 512; kt += 64) {
    {
      k1 = *reinterpret_cast<const bf16x8*>(kp + (size_t)(kt + 32) * 16);
      v01 = vfill; v11 = vfill;
      if (l31 < 16) {
        const unsigned short* vq = vwave + (size_t)(kt + 32) * 16;
        v01 = *reinterpret_cast<const bf16x8*>(vq);
        v11 = *reinterpret_cast<const bf16x8*>(vq + 256);
      }
    }
    attn_tile32(qf, k0, v00, v10, hi8, zeroc, acc);
    if (kt + 64 < 512) {
      k0 = *reinterpret_cast<const bf16x8*>(kp + (size_t)(kt + 64) * 16);
      v00 = vfill; v10 = vfill;
      if (l31 < 16) {
        const unsigned short* vq = vwave + (size_t)(kt + 64) * 16;
        v00 = *reinterpret_cast<const bf16x8*>(vq);
        v10 = *reinterpret_cast<const bf16x8*>(vq + 256);
      }
    }
    attn_tile32(qf, k1, v01, v11, hi8, zeroc, acc);
  }

  {
    float* cb = &comb[wave][lane][0];
    #pragma unroll
    for (int r = 0; r < 9; ++r) cb[r] = acc[r];
  }
  __syncthreads();

  if (wave == 0) {
    float A[9];
    #pragma unroll
    for (int r = 0; r < 9; ++r)
      A[r] = ((comb[0][lane][r] + comb[1][lane][r]) +
              (comb[2][lane][r] + comb[3][lane][r]));
    float L = A[8] + __shfl_xor(A[8], 32);
    float inv = 1.f / L;

    unsigned short oh[8], ol[8];
    #pragma unroll
    for (int r = 0; r < 8; ++r) {
      float o = A[r] * inv;
      oh[r] = bfbits(o);
      ol[r] = bfbits(o - bf2f(oh[r]));
    }
    int b = bh / NH, h = bh % NH;
    int mrow = b * NSQ + q;
    unsigned short* rowp = AOS + (size_t)mrow * (6 * 64);
    int sw = mrow & 7;
    int kblk = h >> 1;
    int cA = (h & 1) * 2;
    unsigned short* p0;
    p0 = rowp + ((kblk*8 + ((cA + 0) ^ sw)) * 8) + 4*hi8;   // hi, d 0-7
    reinterpret_cast<unsigned int*>(p0)[0] = (unsigned)oh[0] | ((unsigned)oh[1] << 16);
    reinterpret_cast<unsigned int*>(p0)[1] = (unsigned)oh[2] | ((unsigned)oh[3] << 16);
    p0 = rowp + ((kblk*8 + ((cA + 1) ^ sw)) * 8) + 4*hi8;   // hi, d 8-15
    reinterpret_cast<unsigned int*>(p0)[0] = (unsigned)oh[4] | ((unsigned)oh[5] << 16);
    reinterpret_cast<unsigned int*>(p0)[1] = (unsigned)oh[6] | ((unsigned)oh[7] << 16);
    p0 = rowp + ((kblk*8 + ((cA + 4) ^ sw)) * 8) + 4*hi8;   // lo, d 0-7
    reinterpret_cast<unsigned int*>(p0)[0] = (unsigned)ol[0] | ((unsigned)ol[1] << 16);
    reinterpret_cast<unsigned int*>(p0)[1] = (unsigned)ol[2] | ((unsigned)ol[3] << 16);
    p0 = rowp + ((kblk*8 + ((cA + 5) ^ sw)) * 8) + 4*hi8;   // lo, d 8-15
    reinterpret_cast<unsigned int*>(p0)[0] = (unsigned)ol[4] | ((unsigned)ol[5] << 16);
    reinterpret_cast<unsigned int*>(p0)[1] = (unsigned)ol[6] | ((unsigned)ol[7] << 16);
  }
}

// ---------------------------------------------------------------------------
// Output projection + XCD-locality remap (m0-major).
// ---------------------------------------------------------------------------
__global__ __launch_bounds__(256) void gemm_out_k(
    const unsigned short* __restrict__ AOS, const unsigned short* __restrict__ WSp,
    const float* __restrict__ bp, float* __restrict__ out) {
  __shared__ unsigned short lds[2 * LDSBUF];
  const int bid = blockIdx.x;
  const int KBLK = NDR / 32;   // 6
  int m0 = (bid & 127) * 64;   // XCD-locality remap (128 % 8 == 0)
  int n0 = (bid >> 7) * 192;
  const unsigned short* As = AOS + (size_t)m0 * KBLK * 64;
  const unsigned short* Ws = WSp + (size_t)n0 * KBLK * 64;
  f32x16 acc[3];
  gemm_core(As, Ws, bp + n0, KBLK, lds, acc);

  const int tid = threadIdx.x;
  const int wv = tid >> 6, lane = tid & 63;
  const int l31 = lane & 31, hi8 = lane >> 5;
  const int wm = wv >> 1, wn = wv & 1;
  #pragma unroll
  for (int nr = 0; nr < 3; ++nr) {
    int n = n0 + wn*96 + nr*32 + l31;
    #pragma unroll
    for (int r = 0; r < 16; ++r) {
      int mg = m0 + wm*32 + (r & 3) + 8*(r >> 2) + 4*hi8;
      out[(size_t)mg * ND + n] = acc[nr][r];
    }
  }
}

extern "C" void kernel_launch(void* const* d_in, const int* in_sizes, int n_in,
                              void* d_out, int out_size, void* d_ws, size_t ws_size,
                              hipStream_t stream) {
  const float* hs  = (const float*)d_in[0];
  const float* ehs = (const float*)d_in[1];
  const float* Wq  = (const float*)d_in[2];
  const float* bq  = (const float*)d_in[3];
  const float* Wkv = (const float*)d_in[4];
  const float* bkv = (const float*)d_in[5];
  const float* Wp  = (const float*)d_in[6];
  const float* bp  = (const float*)d_in[7];
  float* out = (float*)d_out;

  // workspace layout (bytes)
  char* w = (char*)d_ws;
  unsigned short* AOS = (unsigned short*)w;                 // 8192*6*64*2 = 6291456
  char* w2 = w + (size_t)M_TOT * 6 * 64 * 2;
  unsigned short* WSq  = (unsigned short*)w2;                        // 589824
  unsigned short* WSkv = (unsigned short*)(w2 + 589824);             // 1179648
  unsigned short* WSp  = (unsigned short*)(w2 + 589824 + 1179648);   // 589824
  char* w3 = w2 + 589824 + 1179648 + 589824;
  unsigned short* Qbf  = (unsigned short*)w3;               // 3145728
  unsigned short* Kbf  = Qbf + (size_t)M_TOT * NDR;         // 3145728
  unsigned short* VTbf = Kbf + (size_t)M_TOT * NDR;         // 48*256*16*8*2 = 3145728

  prep<<<dim3(72 + 144 + 72), dim3(256), 0, stream>>>(
      Wq, Wkv, Wp, WSq, WSkv, WSp);
  gemm_qkv<<<dim3(768), dim3(384), 0, stream>>>(hs, ehs, WSq, WSkv, bq, bkv, Qbf, Kbf, VTbf);
  attn_bf16<<<dim3(NB * NH * 64), dim3(256), 0, stream>>>(Qbf, Kbf, VTbf, AOS);
  gemm_out_k<<<dim3(512), dim3(256), 0, stream>>>(AOS, WSp, bp, out);
}

// Round 21
// 83.157 us; speedup vs baseline: 1.0147x; 1.0147x over previous
//
#include <hip/hip_runtime.h>
#include <hip/hip_bf16.h>
#include <math.h>

// Problem constants
#define NB 4
#define NSQ 2048
#define NSKV 2048
#define ND 768
#define NH 12
#define NHD 16
#define NDR 192            // NH*NHD
#define M_TOT (NB * NSQ)   // 8192

typedef __attribute__((ext_vector_type(8)))  short          bf16x8;
typedef __attribute__((ext_vector_type(16))) float          f32x16;
typedef __attribute__((ext_vector_type(8)))  unsigned short u16x8;

__device__ __forceinline__ unsigned short bfbits(float x) {
  __hip_bfloat16 h = __float2bfloat16(x);           // hardware RNE cvt
  unsigned short u; __builtin_memcpy(&u, &h, 2); return u;
}
__device__ __forceinline__ float bf2f(unsigned short u) {
  unsigned int v = ((unsigned int)u) << 16; float f; __builtin_memcpy(&f, &v, 4); return f;
}
// P-pack: truncating bf16 pack of two NEVER-NaN positives in ONE v_perm_b32.
__device__ __forceinline__ unsigned int pk2t(float a, float b) {
  unsigned int ua, ub;
  __builtin_memcpy(&ua, &a, 4); __builtin_memcpy(&ub, &b, 4);
#if __has_builtin(__builtin_amdgcn_perm)
  return __builtin_amdgcn_perm(ub, ua, 0x07060302);  // {b.hi16, a.hi16}
#else
  return (ua >> 16) | (ub & 0xffff0000u);
#endif
}
__device__ __forceinline__ float exp2_raw(float x) {
#if __has_builtin(__builtin_amdgcn_exp2f)
  return __builtin_amdgcn_exp2f(x);                 // single v_exp_f32
#else
  float r; asm("v_exp_f32 %0, %1" : "=v"(r) : "v"(x)); return r;
#endif
}
__device__ __forceinline__ void g2l16(const void* g, void* l) {
  __builtin_amdgcn_global_load_lds(
      (const __attribute__((address_space(1))) void*)g,
      (__attribute__((address_space(3))) void*)l, 16, 0, 0);
}

// 0.25 (1/sqrt(HD)) * log2(e): attention runs in exp2 domain
#define QSCALE 0.36067376022224085f
#define LDSBUF 16384   // shorts per dbuf half for gemm_out: (64+192)*64

// ---------------------------------------------------------------------------
// prep: the three weight splits
// (fp32 W [K][N] -> swizzled split-bf16 W^T image [N][KBLK][8][8]).
// ---------------------------------------------------------------------------
__global__ __launch_bounds__(256) void prep(
    const float* __restrict__ Wq, const float* __restrict__ Wkv,
    const float* __restrict__ Wp,
    unsigned short* __restrict__ WSq, unsigned short* __restrict__ WSkv,
    unsigned short* __restrict__ WSp) {
  int bid = blockIdx.x;
  const float* W; unsigned short* out; int Nn, KBLK, bx, by;
  if (bid < 72)        { W = Wq;  out = WSq;  Nn = 192; KBLK = 24; bx = bid % 24;        by = bid / 24; }
  else if (bid < 216)  { int b = bid - 72;  W = Wkv; out = WSkv; Nn = 384; KBLK = 24; bx = b % 24; by = b / 24; }
  else                 { int b = bid - 216; W = Wp;  out = WSp;  Nn = 768; KBLK = 6;  bx = b % 6;  by = b / 6;  }

  __shared__ float tile[32][65];
  int k0 = bx * 32, n0 = by * 64;
  int t = threadIdx.x;
  int kr = t >> 3, c0 = (t & 7) * 8;
  const float* src = W + (size_t)(k0 + kr) * Nn + n0 + c0;
  float4 f0 = *reinterpret_cast<const float4*>(src);
  float4 f1 = *reinterpret_cast<const float4*>(src + 4);
  tile[kr][c0+0] = f0.x; tile[kr][c0+1] = f0.y; tile[kr][c0+2] = f0.z; tile[kr][c0+3] = f0.w;
  tile[kr][c0+4] = f1.x; tile[kr][c0+5] = f1.y; tile[kr][c0+6] = f1.z; tile[kr][c0+7] = f1.w;
  __syncthreads();
  int n = t >> 2, cq0 = (t & 3) * 2;
  int ng = n0 + n, sw = ng & 7;
  unsigned short* dst = out + ((size_t)ng * KBLK + bx) * 64;
  #pragma unroll
  for (int q = 0; q < 2; ++q) {
    int cc = cq0 + q;                // logical chunk 0..7
    u16x8 v;
    #pragma unroll
    for (int i = 0; i < 8; ++i) {
      float x = tile[(cc & 3) * 8 + i][n];
      unsigned short h = bfbits(x);
      v[i] = (cc < 4) ? h : bfbits(x - bf2f(h));
    }
    *reinterpret_cast<u16x8*>(dst + (cc ^ sw) * 8) = v;
  }
}

// ---------------------------------------------------------------------------
// gemm_out core (image-A, double-buffered, 64x192, 4 waves) — unchanged.
// ---------------------------------------------------------------------------
__device__ __forceinline__ void core_compute(
    const unsigned short* const (&ard)[4], const unsigned short* const (&wrd)[12],
    int off, f32x16 (&acc)[3]) {
  #pragma unroll
  for (int kk = 0; kk < 2; ++kk) {
    bf16x8 ah = *reinterpret_cast<const bf16x8*>(ard[kk*2+0] + off);
    bf16x8 al = *reinterpret_cast<const bf16x8*>(ard[kk*2+1] + off);
    #pragma unroll
    for (int nr = 0; nr < 3; ++nr) {
      bf16x8 wh = *reinterpret_cast<const bf16x8*>(wrd[(nr*2+kk)*2+0] + off);
      bf16x8 wl = *reinterpret_cast<const bf16x8*>(wrd[(nr*2+kk)*2+1] + off);
      acc[nr] = __builtin_amdgcn_mfma_f32_32x32x16_bf16(ah, wh, acc[nr], 0, 0, 0);
      acc[nr] = __builtin_amdgcn_mfma_f32_32x32x16_bf16(ah, wl, acc[nr], 0, 0, 0);
      acc[nr] = __builtin_amdgcn_mfma_f32_32x32x16_bf16(al, wh, acc[nr], 0, 0, 0);
    }
  }
}

__device__ __forceinline__ void gemm_core(
    const unsigned short* __restrict__ As,   // pre-offset to m0
    const unsigned short* __restrict__ Ws,   // pre-offset to n0
    const float* __restrict__ bias,          // pre-offset to n0
    int KBLK, unsigned short* lds, f32x16 (&acc)[3]) {
  const int tid = threadIdx.x;
  const int wv = tid >> 6, lane = tid & 63;
  const int l31 = lane & 31, hi8 = lane >> 5;
  const int wm = wv >> 1, wn = wv & 1;

  unsigned short* Ab = lds;
  unsigned short* Wb = lds + 64 * 64;

  const int r8 = lane >> 3, c8 = lane & 7;
  const size_t rowu = (size_t)KBLK * 64;

  const unsigned short* srcA0 = As + (size_t)((0*4 + wv)*8 + r8) * rowu + c8*8;
  const unsigned short* srcA1 = As + (size_t)((1*4 + wv)*8 + r8) * rowu + c8*8;
  const unsigned short* srcW[6];
  #pragma unroll
  for (int j = 0; j < 6; ++j)
    srcW[j] = Ws + (size_t)((j*4 + wv)*8 + r8) * rowu + c8*8;

  unsigned short* dA0 = Ab + ((0*4 + wv)*64 + lane) * 8;
  unsigned short* dA1 = Ab + ((1*4 + wv)*64 + lane) * 8;
  unsigned short* dW[6];
  #pragma unroll
  for (int j = 0; j < 6; ++j)
    dW[j] = Wb + ((j*4 + wv)*64 + lane) * 8;

  const int ra = wm*32 + l31;
  const unsigned short* ard[4];
  #pragma unroll
  for (int kk = 0; kk < 2; ++kk) {
    ard[kk*2+0] = Ab + ra*64 + (((kk*2 + hi8)     ^ (ra & 7)) * 8);
    ard[kk*2+1] = Ab + ra*64 + (((4 + kk*2 + hi8) ^ (ra & 7)) * 8);
  }
  const unsigned short* wrd[12];
  #pragma unroll
  for (int nr = 0; nr < 3; ++nr) {
    int rw = wn*96 + nr*32 + l31;
    #pragma unroll
    for (int kk = 0; kk < 2; ++kk) {
      wrd[(nr*2+kk)*2+0] = Wb + rw*64 + (((kk*2 + hi8)     ^ (rw & 7)) * 8);
      wrd[(nr*2+kk)*2+1] = Wb + rw*64 + (((4 + kk*2 + hi8) ^ (rw & 7)) * 8);
    }
  }

  #pragma unroll
  for (int nr = 0; nr < 3; ++nr) {
    float bv = bias[wn*96 + nr*32 + l31];
    #pragma unroll
    for (int r = 0; r < 16; ++r) acc[nr][r] = bv;
  }

  g2l16(srcA0, dA0); srcA0 += 64;
  g2l16(srcA1, dA1); srcA1 += 64;
  #pragma unroll
  for (int j = 0; j < 6; ++j) { g2l16(srcW[j], dW[j]); srcW[j] += 64; }
  __syncthreads();

  for (int kb = 0; kb < KBLK; kb += 2) {
    if (kb + 1 < KBLK) {
      g2l16(srcA0, dA0 + LDSBUF); srcA0 += 64;
      g2l16(srcA1, dA1 + LDSBUF); srcA1 += 64;
      #pragma unroll
      for (int j = 0; j < 6; ++j) { g2l16(srcW[j], dW[j] + LDSBUF); srcW[j] += 64; }
    }
    core_compute(ard, wrd, 0, acc);
    __syncthreads();
    if (kb + 2 < KBLK) {
      g2l16(srcA0, dA0); srcA0 += 64;
      g2l16(srcA1, dA1); srcA1 += 64;
      #pragma unroll
      for (int j = 0; j < 6; ++j) { g2l16(srcW[j], dW[j]); srcW[j] += 64; }
    }
    core_compute(ard, wrd, LDSBUF, acc);
    __syncthreads();
  }
}

// ---------------------------------------------------------------------------
// Fused Q/KV projection (R16 verified, 64x96 tiles, 6 waves, 40 KiB dbuf)
// + XCD-locality remap: blocks sharing an A-tile land on one XCD.
// ---------------------------------------------------------------------------
#define QHALF 10240   // shorts per buffer: A 64x64 + W 96x64
__global__ __launch_bounds__(384) void gemm_qkv(
    const float* __restrict__ A1, const float* __restrict__ A2,
    const unsigned short* __restrict__ WSq, const unsigned short* __restrict__ WSkv,
    const float* __restrict__ bq, const float* __restrict__ bkv,
    unsigned short* __restrict__ Qbf, unsigned short* __restrict__ Kbf,
    unsigned short* __restrict__ VTbf) {
  __shared__ unsigned short lds[2 * QHALF];   // 40 KiB
  const int bid = blockIdx.x;
  const float* Afp; const unsigned short* Ws; const float* bias;
  int m0, mode, ntile;
  if (bid < 256) {
    mode = 0; ntile = (bid >> 7) * 96;        // XCD remap: mt-major
    Afp = A1; Ws = WSq + (size_t)ntile * (24*64); bias = bq + ntile;
    m0 = (bid & 127) * 64;
  } else {
    int b2 = bid - 256;
    int sub = b2 >> 7;                        // XCD remap: mt-major
    m0 = (b2 & 127) * 64;
    Afp = A2;
    if (sub < 2) { mode = 1; ntile = sub * 96;
                   Ws = WSkv + (size_t)ntile * (24*64); bias = bkv + ntile; }
    else         { mode = 2; ntile = (sub - 2) * 96;
                   Ws = WSkv + (size_t)(192 + ntile) * (24*64); bias = bkv + 192 + ntile; }
  }
  Afp += (size_t)m0 * ND;

  const int tid = threadIdx.x;
  const int wv = tid >> 6, lane = tid & 63;
  const int l31 = lane & 31, hi8 = lane >> 5;
  const int wm = wv & 1, wn = wv >> 1;    // wm 0..1 (rows), wn 0..2 (cols)

  unsigned short* Ab = lds;               // [64][64]
  unsigned short* Wb = lds + 64*64;       // [96][64]

  // A staging (threads 0..255): row ar, fp32 quad cq
  const int ar = tid >> 2, cq = tid & 3;
  const bool doA = (tid < 256);
  const float* srcA = Afp + (size_t)(doA ? ar : 0) * ND + cq*8;
  unsigned short* dAh = Ab + (doA ? ar : 0)*64 + ((cq       ^ (ar & 7)) * 8);
  unsigned short* dAl = Ab + (doA ? ar : 0)*64 + (((cq + 4) ^ (ar & 7)) * 8);

  // W staging: 2 physical chunks per thread (768 = 96 rows x 8)
  const int wch0 = tid, wch1 = tid + 384;
  const unsigned short* srcW0 = Ws + (size_t)(wch0 >> 3) * (24*64) + (wch0 & 7) * 8;
  const unsigned short* srcW1 = Ws + (size_t)(wch1 >> 3) * (24*64) + (wch1 & 7) * 8;
  unsigned short* dW0 = Wb + wch0 * 8;
  unsigned short* dW1 = Wb + wch1 * 8;

  // read-side fragment pointers (verified XOR-swizzle algebra)
  const int ra = wm*32 + l31;
  const int rw = wn*32 + l31;
  const unsigned short* ard[4];
  const unsigned short* wrd[4];
  #pragma unroll
  for (int kk = 0; kk < 2; ++kk) {
    ard[kk*2+0] = Ab + ra*64 + (((kk*2 + hi8)     ^ (ra & 7)) * 8);
    ard[kk*2+1] = Ab + ra*64 + (((4 + kk*2 + hi8) ^ (ra & 7)) * 8);
    wrd[kk*2+0] = Wb + rw*64 + (((kk*2 + hi8)     ^ (rw & 7)) * 8);
    wrd[kk*2+1] = Wb + rw*64 + (((4 + kk*2 + hi8) ^ (rw & 7)) * 8);
  }

  f32x16 acc;
  {
    float bv = bias[wn*32 + l31];
    #pragma unroll
    for (int r = 0; r < 16; ++r) acc[r] = bv;
  }

  // ---- prologue: stage k-step 0 -> buf0
  {
    g2l16(srcW0, dW0); srcW0 += 64;
    g2l16(srcW1, dW1); srcW1 += 64;
    if (doA) {
      float4 f0 = *reinterpret_cast<const float4*>(srcA);
      float4 f1 = *reinterpret_cast<const float4*>(srcA + 4);
      float x[8] = {f0.x, f0.y, f0.z, f0.w, f1.x, f1.y, f1.z, f1.w};
      u16x8 hv, lv;
      #pragma unroll
      for (int i = 0; i < 8; ++i) {
        unsigned short h = bfbits(x[i]);
        hv[i] = h; lv[i] = bfbits(x[i] - bf2f(h));
      }
      *reinterpret_cast<u16x8*>(dAh) = hv;
      *reinterpret_cast<u16x8*>(dAl) = lv;
    }
    srcA += 32;
  }
  __syncthreads();

  #define QKV_COMPUTE(off)                                                     \
    {                                                                          \
      _Pragma("unroll")                                                        \
      for (int kk = 0; kk < 2; ++kk) {                                         \
        bf16x8 ah = *reinterpret_cast<const bf16x8*>(ard[kk*2+0] + (off));     \
        bf16x8 al = *reinterpret_cast<const bf16x8*>(ard[kk*2+1] + (off));     \
        bf16x8 wh = *reinterpret_cast<const bf16x8*>(wrd[kk*2+0] + (off));     \
        bf16x8 wl = *reinterpret_cast<const bf16x8*>(wrd[kk*2+1] + (off));     \
        acc = __builtin_amdgcn_mfma_f32_32x32x16_bf16(ah, wh, acc, 0, 0, 0);   \
        acc = __builtin_amdgcn_mfma_f32_32x32x16_bf16(ah, wl, acc, 0, 0, 0);   \
        acc = __builtin_amdgcn_mfma_f32_32x32x16_bf16(al, wh, acc, 0, 0, 0);   \
      }                                                                        \
    }

  for (int kb = 0; kb < 24; kb += 2) {
    // phase A: stage kb+1 -> buf1, compute buf0
    float4 f0, f1;
    g2l16(srcW0, dW0 + QHALF); srcW0 += 64;
    g2l16(srcW1, dW1 + QHALF); srcW1 += 64;
    if (doA) {
      f0 = *reinterpret_cast<const float4*>(srcA);
      f1 = *reinterpret_cast<const float4*>(srcA + 4);
    }
    srcA += 32;
    QKV_COMPUTE(0)
    if (doA) {
      float x[8] = {f0.x, f0.y, f0.z, f0.w, f1.x, f1.y, f1.z, f1.w};
      u16x8 hv, lv;
      #pragma unroll
      for (int i = 0; i < 8; ++i) {
        unsigned short h = bfbits(x[i]);
        hv[i] = h; lv[i] = bfbits(x[i] - bf2f(h));
      }
      *reinterpret_cast<u16x8*>(dAh + QHALF) = hv;
      *reinterpret_cast<u16x8*>(dAl + QHALF) = lv;
    }
    __syncthreads();
    // phase B: stage kb+2 -> buf0, compute buf1
    bool has2 = (kb + 2 < 24);
    if (has2) {
      g2l16(srcW0, dW0); srcW0 += 64;
      g2l16(srcW1, dW1); srcW1 += 64;
      if (doA) {
        f0 = *reinterpret_cast<const float4*>(srcA);
        f1 = *reinterpret_cast<const float4*>(srcA + 4);
      }
      srcA += 32;
    }
    QKV_COMPUTE(QHALF)
    if (has2 && doA) {
      float x[8] = {f0.x, f0.y, f0.z, f0.w, f1.x, f1.y, f1.z, f1.w};
      u16x8 hv, lv;
      #pragma unroll
      for (int i = 0; i < 8; ++i) {
        unsigned short h = bfbits(x[i]);
        hv[i] = h; lv[i] = bfbits(x[i] - bf2f(h));
      }
      *reinterpret_cast<u16x8*>(dAh) = hv;
      *reinterpret_cast<u16x8*>(dAl) = lv;
    }
    __syncthreads();
  }
  #undef QKV_COMPUTE

  // ---- epilogues
  if (mode == 2) {
    // V: transpose via LDS -> VT2 [bh][key/8][16d][8key]
    unsigned short (*tile)[65] = reinterpret_cast<unsigned short(*)[65]>(lds);
    #pragma unroll
    for (int r = 0; r < 16; ++r) {
      int key_l = wm*32 + (r & 3) + 8*(r >> 2) + 4*hi8;   // 0..63
      tile[wn*32 + l31][key_l] = bfbits(acc[r]);
    }
    __syncthreads();
    int b = m0 >> 11, key0 = m0 & 2047;
    #pragma unroll
    for (int j = 0; j < 2; ++j) {
      int flat = j * 384 + tid;        // 0..767
      int row = flat >> 3;             // 0..95 local V-col
      int ck = flat & 7;               // 8-key chunk within the 64 keys
      int vcol = ntile + row;
      int h = vcol >> 4, d = vcol & 15;
      u16x8 v;
      #pragma unroll
      for (int jj = 0; jj < 8; ++jj) v[jj] = tile[row][ck*8 + jj];
      *reinterpret_cast<u16x8*>(
          &VTbf[(((size_t)(b*NH + h)*256 + (key0 >> 3) + ck)*16 + d)*8]) = v;
    }
    return;
  }

  unsigned short* outp = (mode == 0) ? Qbf : Kbf;
  const float scale = (mode == 0) ? QSCALE : 1.0f;
  {
    int col = ntile + wn*32 + l31;      // 0..191
    int h = col >> 4, d = col & 15;
    #pragma unroll
    for (int r = 0; r < 16; ++r) {
      int mg = m0 + wm*32 + (r & 3) + 8*(r >> 2) + 4*hi8;
      int b = mg >> 11, q = mg & 2047;
      outp[(((size_t)b*NH + h)*NSQ + q)*16 + d] = bfbits(acc[r] * scale);
    }
  }
}

// ---------------------------------------------------------------------------
// attn dual-q 32-key tile: ONE K/V tile feeds TWO q-row groups (6 MFMAs per
// 3 loads — 2x arithmetic intensity vs single). Verified per-group algebra.
// ---------------------------------------------------------------------------
__device__ __forceinline__ void attn_tile32x2(
    bf16x8 qfA, bf16x8 qfB, bf16x8 kf, bf16x8 vf0, bf16x8 vf1,
    int hi8, const f32x16& zeroc, f32x16& accA, f32x16& accB) {
  f32x16 sA = __builtin_amdgcn_mfma_f32_32x32x16_bf16(kf, qfA, zeroc, 0, 0, 0);
  f32x16 sB = __builtin_amdgcn_mfma_f32_32x32x16_bf16(kf, qfB, zeroc, 0, 0, 0);

  float pA[16], pB[16];
  #pragma unroll
  for (int r = 0; r < 16; ++r) { pA[r] = exp2_raw(sA[r]); pB[r] = exp2_raw(sB[r]); }

  unsigned int wA[8], wB[8];
  #pragma unroll
  for (int t8 = 0; t8 < 8; ++t8) {
    wA[t8] = pk2t(pA[2*t8], pA[2*t8+1]);
    wB[t8] = pk2t(pB[2*t8], pB[2*t8+1]);
  }

  unsigned int tA0 = hi8 ? wA[0] : wA[2], tA1 = hi8 ? wA[1] : wA[3];
  unsigned int tA2 = hi8 ? wA[4] : wA[6], tA3 = hi8 ? wA[5] : wA[7];
  unsigned int tB0 = hi8 ? wB[0] : wB[2], tB1 = hi8 ? wB[1] : wB[3];
  unsigned int tB2 = hi8 ? wB[4] : wB[6], tB3 = hi8 ? wB[5] : wB[7];
  unsigned int rA0 = (unsigned int)__shfl_xor((int)tA0, 32);
  unsigned int rA1 = (unsigned int)__shfl_xor((int)tA1, 32);
  unsigned int rA2 = (unsigned int)__shfl_xor((int)tA2, 32);
  unsigned int rA3 = (unsigned int)__shfl_xor((int)tA3, 32);
  unsigned int rB0 = (unsigned int)__shfl_xor((int)tB0, 32);
  unsigned int rB1 = (unsigned int)__shfl_xor((int)tB1, 32);
  unsigned int rB2 = (unsigned int)__shfl_xor((int)tB2, 32);
  unsigned int rB3 = (unsigned int)__shfl_xor((int)tB3, 32);

  union { bf16x8 v; unsigned int u[4]; } pa0A, pa1A, pa0B, pa1B;
  pa0A.u[0] = hi8 ? rA0 : wA[0];  pa0A.u[1] = hi8 ? rA1 : wA[1];
  pa0A.u[2] = hi8 ? wA[2] : rA0;  pa0A.u[3] = hi8 ? wA[3] : rA1;
  pa1A.u[0] = hi8 ? rA2 : wA[4];  pa1A.u[1] = hi8 ? rA3 : wA[5];
  pa1A.u[2] = hi8 ? wA[6] : rA2;  pa1A.u[3] = hi8 ? wA[7] : rA3;
  pa0B.u[0] = hi8 ? rB0 : wB[0];  pa0B.u[1] = hi8 ? rB1 : wB[1];
  pa0B.u[2] = hi8 ? wB[2] : rB0;  pa0B.u[3] = hi8 ? wB[3] : rB1;
  pa1B.u[0] = hi8 ? rB2 : wB[4];  pa1B.u[1] = hi8 ? rB3 : wB[5];
  pa1B.u[2] = hi8 ? wB[6] : rB2;  pa1B.u[3] = hi8 ? wB[7] : rB3;

  __builtin_amdgcn_s_setprio(1);
  accA = __builtin_amdgcn_mfma_f32_32x32x16_bf16(vf0, pa0A.v, accA, 0, 0, 0);
  accB = __builtin_amdgcn_mfma_f32_32x32x16_bf16(vf0, pa0B.v, accB, 0, 0, 0);
  accA = __builtin_amdgcn_mfma_f32_32x32x16_bf16(vf1, pa1A.v, accA, 0, 0, 0);
  accB = __builtin_amdgcn_mfma_f32_32x32x16_bf16(vf1, pa1B.v, accB, 0, 0, 0);
  __builtin_amdgcn_s_setprio(0);
}

// ---------------------------------------------------------------------------
// MFMA attention, dual-q: block owns 64 q-rows (2 groups of 32); each K/V
// tile is shared by both groups. KV-split x4, exp2, fixed max, constant pad
// rows, coalesced VT2 loads, register-dbuf prefetch, XCD remap (bh=bid%48).
// ---------------------------------------------------------------------------
__global__ __launch_bounds__(256, 3) void attn_bf16(
    const unsigned short* __restrict__ Qbf, const unsigned short* __restrict__ Kbf,
    const unsigned short* __restrict__ VT, unsigned short* __restrict__ AOS) {
  __shared__ float comb[2][4][64][9];   // 18 KiB
  const int tid = threadIdx.x;
  const int wave = tid >> 6, lane = tid & 63;
  const int l31 = lane & 31, hi8 = lane >> 5;
  const int bid = blockIdx.x;
  const int bh = bid % 48;           // XCD-locality remap (48 % 8 == 0)
  const int qt = bid / 48;           // 32 q-tiles of 64 rows

  const unsigned short* qp = &Qbf[((size_t)bh*NSQ + qt*64 + l31)*16 + hi8*8];
  bf16x8 qfA = *reinterpret_cast<const bf16x8*>(qp);
  bf16x8 qfB = *reinterpret_cast<const bf16x8*>(qp + 32*16);
  const unsigned short* kbase = Kbf + (size_t)bh * NSKV * 16;

  const short fillv = (l31 == 16) ? (short)0x3F80 : (short)0;
  bf16x8 vfill;
  #pragma unroll
  for (int j = 0; j < 8; ++j) vfill[j] = fillv;

  f32x16 accA, accB;
  #pragma unroll
  for (int r = 0; r < 16; ++r) { accA[r] = 0.f; accB[r] = 0.f; }
  const f32x16 zeroc = accA;

  const int kstart = wave * (NSKV / 4);   // 512 keys per wave
  const unsigned short* kp = &kbase[(size_t)(kstart + l31)*16 + hi8*8];
  const unsigned short* vwave = VT + ((((size_t)bh*256 + (kstart >> 3) + hi8)*16 + l31) * 8);

  bf16x8 k0, v00, v10;
  bf16x8 k1, v01, v11;

  k0  = *reinterpret_cast<const bf16x8*>(kp);
  v00 = vfill; v10 = vfill;
  if (l31 < 16) {
    v00 = *reinterpret_cast<const bf16x8*>(vwave);
    v10 = *reinterpret_cast<const bf16x8*>(vwave + 256);
  }

  for (int kt = 0; kt < 512; kt += 64) {
    {
      k1 = *reinterpret_cast<const bf16x8*>(kp + (size_t)(kt + 32) * 16);
      v01 = vfill; v11 = vfill;
      if (l31 < 16) {
        const unsigned short* vq = vwave + (size_t)(kt + 32) * 16;
        v01 = *reinterpret_cast<const bf16x8*>(vq);
        v11 = *reinterpret_cast<const bf16x8*>(vq + 256);
      }
    }
    attn_tile32x2(qfA, qfB, k0, v00, v10, hi8, zeroc, accA, accB);
    if (kt + 64 < 512) {
      k0 = *reinterpret_cast<const bf16x8*>(kp + (size_t)(kt + 64) * 16);
      v00 = vfill; v10 = vfill;
      if (l31 < 16) {
        const unsigned short* vq = vwave + (size_t)(kt + 64) * 16;
        v00 = *reinterpret_cast<const bf16x8*>(vq);
        v10 = *reinterpret_cast<const bf16x8*>(vq + 256);
      }
    }
    attn_tile32x2(qfA, qfB, k1, v01, v11, hi8, zeroc, accA, accB);
  }

  {
    float* cbA = &comb[0][wave][lane][0];
    float* cbB = &comb[1][wave][lane][0];
    #pragma unroll
    for (int r = 0; r < 9; ++r) { cbA[r] = accA[r]; cbB[r] = accB[r]; }
  }
  __syncthreads();

  if (wave < 2) {
    const int g = wave;                 // wave 0 -> group A, wave 1 -> group B
    float A[9];
    #pragma unroll
    for (int r = 0; r < 9; ++r)
      A[r] = ((comb[g][0][lane][r] + comb[g][1][lane][r]) +
              (comb[g][2][lane][r] + comb[g][3][lane][r]));
    float L = A[8] + __shfl_xor(A[8], 32);   // ones-row sum
    float inv = 1.f / L;

    unsigned short oh[8], ol[8];
    #pragma unroll
    for (int r = 0; r < 8; ++r) {
      float o = A[r] * inv;
      oh[r] = bfbits(o);
      ol[r] = bfbits(o - bf2f(oh[r]));
    }
    int b = bh / NH, h = bh % NH;
    int q = qt*64 + g*32 + l31;
    int mrow = b * NSQ + q;
    unsigned short* rowp = AOS + (size_t)mrow * (6 * 64);
    int sw = mrow & 7;
    int kblk = h >> 1;
    int cA = (h & 1) * 2;
    unsigned short* p0;
    p0 = rowp + ((kblk*8 + ((cA + 0) ^ sw)) * 8) + 4*hi8;   // hi, d 0-7
    reinterpret_cast<unsigned int*>(p0)[0] = (unsigned)oh[0] | ((unsigned)oh[1] << 16);
    reinterpret_cast<unsigned int*>(p0)[1] = (unsigned)oh[2] | ((unsigned)oh[3] << 16);
    p0 = rowp + ((kblk*8 + ((cA + 1) ^ sw)) * 8) + 4*hi8;   // hi, d 8-15
    reinterpret_cast<unsigned int*>(p0)[0] = (unsigned)oh[4] | ((unsigned)oh[5] << 16);
    reinterpret_cast<unsigned int*>(p0)[1] = (unsigned)oh[6] | ((unsigned)oh[7] << 16);
    p0 = rowp + ((kblk*8 + ((cA + 4) ^ sw)) * 8) + 4*hi8;   // lo, d 0-7
    reinterpret_cast<unsigned int*>(p0)[0] = (unsigned)ol[0] | ((unsigned)ol[1] << 16);
    reinterpret_cast<unsigned int*>(p0)[1] = (unsigned)ol[2] | ((unsigned)ol[3] << 16);
    p0 = rowp + ((kblk*8 + ((cA + 5) ^ sw)) * 8) + 4*hi8;   // lo, d 8-15
    reinterpret_cast<unsigned int*>(p0)[0] = (unsigned)ol[4] | ((unsigned)ol[5] << 16);
    reinterpret_cast<unsigned int*>(p0)[1] = (unsigned)ol[6] | ((unsigned)ol[7] << 16);
  }
}

// ---------------------------------------------------------------------------
// Output projection + XCD-locality remap (m0-major).
// ---------------------------------------------------------------------------
__global__ __launch_bounds__(256) void gemm_out_k(
    const unsigned short* __restrict__ AOS, const unsigned short* __restrict__ WSp,
    const float* __restrict__ bp, float* __restrict__ out) {
  __shared__ unsigned short lds[2 * LDSBUF];
  const int bid = blockIdx.x;
  const int KBLK = NDR / 32;   // 6
  int m0 = (bid & 127) * 64;   // XCD-locality remap (128 % 8 == 0)
  int n0 = (bid >> 7) * 192;
  const unsigned short* As = AOS + (size_t)m0 * KBLK * 64;
  const unsigned short* Ws = WSp + (size_t)n0 * KBLK * 64;
  f32x16 acc[3];
  gemm_core(As, Ws, bp + n0, KBLK, lds, acc);

  const int tid = threadIdx.x;
  const int wv = tid >> 6, lane = tid & 63;
  const int l31 = lane & 31, hi8 = lane >> 5;
  const int wm = wv >> 1, wn = wv & 1;
  #pragma unroll
  for (int nr = 0; nr < 3; ++nr) {
    int n = n0 + wn*96 + nr*32 + l31;
    #pragma unroll
    for (int r = 0; r < 16; ++r) {
      int mg = m0 + wm*32 + (r & 3) + 8*(r >> 2) + 4*hi8;
      out[(size_t)mg * ND + n] = acc[nr][r];
    }
  }
}

extern "C" void kernel_launch(void* const* d_in, const int* in_sizes, int n_in,
                              void* d_out, int out_size, void* d_ws, size_t ws_size,
                              hipStream_t stream) {
  const float* hs  = (const float*)d_in[0];
  const float* ehs = (const float*)d_in[1];
  const float* Wq  = (const float*)d_in[2];
  const float* bq  = (const float*)d_in[3];
  const float* Wkv = (const float*)d_in[4];
  const float* bkv = (const float*)d_in[5];
  const float* Wp  = (const float*)d_in[6];
  const float* bp  = (const float*)d_in[7];
  float* out = (float*)d_out;

  // workspace layout (bytes)
  char* w = (char*)d_ws;
  unsigned short* AOS = (unsigned short*)w;                 // 8192*6*64*2 = 6291456
  char* w2 = w + (size_t)M_TOT * 6 * 64 * 2;
  unsigned short* WSq  = (unsigned short*)w2;                        // 589824
  unsigned short* WSkv = (unsigned short*)(w2 + 589824);             // 1179648
  unsigned short* WSp  = (unsigned short*)(w2 + 589824 + 1179648);   // 589824
  char* w3 = w2 + 589824 + 1179648 + 589824;
  unsigned short* Qbf  = (unsigned short*)w3;               // 3145728
  unsigned short* Kbf  = Qbf + (size_t)M_TOT * NDR;         // 3145728
  unsigned short* VTbf = Kbf + (size_t)M_TOT * NDR;         // 48*256*16*8*2 = 3145728

  prep<<<dim3(72 + 144 + 72), dim3(256), 0, stream>>>(
      Wq, Wkv, Wp, WSq, WSkv, WSp);
  gemm_qkv<<<dim3(768), dim3(384), 0, stream>>>(hs, ehs, WSq, WSkv, bq, bkv, Qbf, Kbf, VTbf);
  attn_bf16<<<dim3(NB * NH * 32), dim3(256), 0, stream>>>(Qbf, Kbf, VTbf, AOS);
  gemm_out_k<<<dim3(512), dim3(256), 0, stream>>>(AOS, WSp, bp, out);
}